// Round 7
// baseline (18588.382 us; speedup 1.0000x reference)
//
#include <hip/hip_runtime.h>
#include <hip/hip_bf16.h>
#include <math.h>
#include <stdint.h>

#define KDIM   2048
#define TSTEPS 1024
#define NNZ    4096
#define BEAMS  16
#define NWG    16               // one workgroup per beam
#define EPT    16               // evals per thread (NNZ / 256)
#define LCAP   4096             // LDS candidate capacity == max possible

// posterior in the reference's exact association order:
// ((lps + d) + ((v0 - m0) - L0)) + ((v1 - m1) - L1)
__device__ __forceinline__ float post_val(float lpsb, float d,
                                          float v0, float mm0, float ll0,
                                          float v1, float mm1, float ll1) {
    return ((lpsb + d) + ((v0 - mm0) - ll0)) + ((v1 - mm1) - ll1);
}

// order-preserving float<->uint32 map
__device__ __forceinline__ uint32_t ord_enc(float f) {
    uint32_t u = __float_as_uint(f);
    return (u & 0x80000000u) ? ~u : (u | 0x80000000u);
}
__device__ __forceinline__ float ord_dec(uint32_t u) {
    return __uint_as_float((u & 0x80000000u) ? (u & 0x7FFFFFFFu) : ~u);
}

__device__ __forceinline__ int lane_offset(uint64_t mask) {
    return __builtin_amdgcn_mbcnt_hi((uint32_t)(mask >> 32),
           __builtin_amdgcn_mbcnt_lo((uint32_t)mask, 0u));
}

// ---------- kernel 1: scaled tables = prior / 0.7 (true IEEE divide) ----------
__global__ void scale_kernel(const float* __restrict__ p0,
                             const float* __restrict__ p1,
                             float* __restrict__ sc) {
    const int NF4 = (KDIM * KDIM) / 4;
    int i = blockIdx.x * blockDim.x + threadIdx.x;
    float4 v;
    if (i < NF4) v = ((const float4*)p0)[i];
    else         v = ((const float4*)p1)[i - NF4];
    v.x = v.x / 0.7f; v.y = v.y / 0.7f; v.z = v.z / 0.7f; v.w = v.w / 0.7f;
    ((float4*)sc)[i] = v;
}

// ---------- kernel 2: per-row max + log-sum-exp of the scaled rows ----------
__global__ void rowstat_kernel(const float* __restrict__ sc,
                               float* __restrict__ mArr,
                               float* __restrict__ lArr) {
    __shared__ float red[4];
    __shared__ float bm;
    const int r = blockIdx.x;
    const float* row = sc + (size_t)r * KDIM;
    const int tid = threadIdx.x;
    const int lane = tid & 63, wv = tid >> 6;

    float4 a = ((const float4*)row)[tid];
    float4 b = ((const float4*)row)[tid + 256];
    float m = fmaxf(fmaxf(fmaxf(a.x, a.y), fmaxf(a.z, a.w)),
                    fmaxf(fmaxf(b.x, b.y), fmaxf(b.z, b.w)));
    for (int s = 32; s; s >>= 1) m = fmaxf(m, __shfl_xor(m, s));
    if (lane == 0) red[wv] = m;
    __syncthreads();
    if (tid == 0) bm = fmaxf(fmaxf(red[0], red[1]), fmaxf(red[2], red[3]));
    __syncthreads();
    const float mm = bm;

    float s = expf(a.x - mm);
    s += expf(a.y - mm); s += expf(a.z - mm); s += expf(a.w - mm);
    s += expf(b.x - mm); s += expf(b.y - mm); s += expf(b.z - mm); s += expf(b.w - mm);
    for (int sh = 32; sh; sh >>= 1) s += __shfl_xor(s, sh);
    __syncthreads();
    if (lane == 0) red[wv] = s;
    __syncthreads();
    if (tid == 0) {
        float S = ((red[0] + red[1]) + red[2]) + red[3];
        mArr[r] = mm;
        lArr[r] = logf(S);
    }
}

// float-only 64-lane bitonic (descending): returns 16th-largest, broadcast
__device__ __forceinline__ float wave16th_f(float v, int lane) {
    for (int k = 2; k <= 64; k <<= 1) {
        for (int j = k >> 1; j > 0; j >>= 1) {
            float ov = __shfl_xor(v, j);
            bool lower = (lane & j) == 0;
            bool up    = (lane & k) == 0;
            bool iwin  = v > ov;
            bool take  = (lower == up) ? !iwin : iwin;
            if (take) v = ov;
        }
    }
    return __shfl(v, 15);
}

// u64 64-lane bitonic sort (descending): rank r lands in lane r
__device__ __forceinline__ uint64_t bsort64(uint64_t v, int lane) {
    for (int k = 2; k <= 64; k <<= 1) {
        for (int j = k >> 1; j > 0; j >>= 1) {
            uint64_t ov = __shfl_xor((unsigned long long)v, j);
            bool lower = (lane & j) == 0;
            bool up    = (lane & k) == 0;
            bool iwin  = v > ov;
            bool take  = (lower == up) ? !iwin : iwin;
            if (take) v = ov;
        }
    }
    return v;
}

// wave0: exact sorted top-16 of lds[0..C) (u64 desc). Lane r<16 returns rank r.
// Values are unique and nonzero by construction; 0 is the -inf sentinel.
__device__ __forceinline__ uint64_t wave_sel16_u64(int C, uint64_t* lds, int lane) {
    if (C <= 64) {
        uint64_t v = (lane < C) ? lds[lane] : 0;
        return bsort64(v, lane);
    }
    uint64_t res = 0;
    for (int rk = 0; rk < BEAMS; ++rk) {
        uint64_t bv = 0; int bj = -1;
        for (int j = lane; j < C; j += 64) {
            uint64_t v = lds[j];
            if (v > bv) { bv = v; bj = j; }
        }
        for (int s = 32; s; s >>= 1) {
            uint64_t ov = __shfl_xor((unsigned long long)bv, s);
            int      oj = __shfl_xor(bj, s);
            if (ov > bv) { bv = ov; bj = oj; }
        }
        if (lane == 0 && bj >= 0) lds[bj] = 0;
        if (lane == rk) res = bv;
    }
    return res;
}

// ---------- kernel 3: 16 WGs, commit-word data-flag sync, LDS row stats ----------
__global__ __launch_bounds__(256, 1) void beam_kernel(
    const float* __restrict__ sc,        // [2*2048][2048] scaled tables
    const float* __restrict__ mArr,      // [4096]
    const float* __restrict__ lArr,      // [4096]
    const float* __restrict__ ll_data,   // [1024][4096]
    const int*   __restrict__ ll_coords, // [1024][2][4096]
    const int*   __restrict__ x0i,
    const int*   __restrict__ x1i,
    float* __restrict__ out,
    uint64_t* __restrict__ gslot,        // [2][NWG*16] packed candidates
    uint64_t* __restrict__ gcommit)      // [2][NWG] commit words, 64B stride
{
    __shared__ float    wred[4];
    __shared__ int      scnt;
    __shared__ uint64_t cand_pk[LCAP];   // 32 KB
    __shared__ float    smArr[2 * KDIM]; // 16 KB — row stats cached in LDS
    __shared__ float    slArr[2 * KDIM]; // 16 KB
    __shared__ uint64_t headq[NWG];
    __shared__ uint64_t respk[BEAMS];

    const int tid  = threadIdx.x;
    const int lane = tid & 63;
    const int wv   = tid >> 6;
    const int b    = blockIdx.x;              // this WG's beam
    const float* sc1 = sc + (size_t)KDIM * KDIM;
    const int n0 = tid * EPT;

    // cache per-row normalizer stats in LDS (one-time, 32 KB)
    for (int i = tid; i < 2 * KDIM; i += 256) {
        smArr[i] = mArr[i];
        slArr[i] = lArr[i];
    }

    // beam state in registers (uniform across the WG)
    int   r0i  = x0i[b];
    int   r1i  = x1i[b];
    float lpsb = 0.0f;

    // prefetch step 0 stream data into registers
    float4 pf_d[4]; int4 pf_a[4], pf_b[4];
#pragma unroll
    for (int j = 0; j < 4; ++j) {
        pf_d[j] = *(const float4*)(ll_data + n0 + 4 * j);
        pf_a[j] = *(const int4*)(ll_coords + n0 + 4 * j);
        pf_b[j] = *(const int4*)(ll_coords + NNZ + n0 + 4 * j);
    }
    __syncthreads();

#pragma unroll 1
    for (int t = 0; t < TSTEPS; ++t) {
        const int* cp = ll_coords + (size_t)t * 2 * NNZ;
        uint64_t* slots  = gslot + (size_t)(t & 1) * (NWG * BEAMS);
        uint64_t* commit = gcommit + (size_t)(t & 1) * (NWG * 8);
        const uint32_t tag = (uint32_t)(t + 1);   // never matches 0xAAAA poison

        if (tid == 0) scnt = 0;

        // ---- eval: 16 posteriors/thread, gathers from L1/L2/LLC ----
        const float* r0 = sc  + (size_t)r0i * KDIM;
        const float* r1 = sc1 + (size_t)r1i * KDIM;
        const float mm0 = smArr[r0i],        ll0 = slArr[r0i];
        const float mm1 = smArr[KDIM + r1i], ll1 = slArr[KDIM + r1i];

        float p[EPT];
        float best = -INFINITY;
#pragma unroll
        for (int j = 0; j < 4; ++j) {
            float4 d4 = pf_d[j]; int4 a4 = pf_a[j]; int4 b4 = pf_b[j];
            float va0 = r0[a4.x], va1 = r0[a4.y], va2 = r0[a4.z], va3 = r0[a4.w];
            float vb0 = r1[b4.x], vb1 = r1[b4.y], vb2 = r1[b4.z], vb3 = r1[b4.w];
            p[4*j+0] = post_val(lpsb, d4.x, va0, mm0, ll0, vb0, mm1, ll1);
            p[4*j+1] = post_val(lpsb, d4.y, va1, mm0, ll0, vb1, mm1, ll1);
            p[4*j+2] = post_val(lpsb, d4.z, va2, mm0, ll0, vb2, mm1, ll1);
            p[4*j+3] = post_val(lpsb, d4.w, va3, mm0, ll0, vb3, mm1, ll1);
            best = fmaxf(best, fmaxf(fmaxf(p[4*j+0], p[4*j+1]), fmaxf(p[4*j+2], p[4*j+3])));
        }

        // tau = max over waves of (16th-largest lane-best): valid lower bound
        float w16 = wave16th_f(best, lane);
        if (lane == 0) wred[wv] = w16;
        __syncthreads();                                     // S1
        const float tau = fmaxf(fmaxf(wred[0], wred[1]), fmaxf(wred[2], wred[3]));

        // prefetch next step's stream; loads fly under select/publish/poll
        {
            const int tp = (t + 1 < TSTEPS) ? t + 1 : t;
            const float* dp2 = ll_data + (size_t)tp * NNZ;
            const int*   cp2 = ll_coords + (size_t)tp * 2 * NNZ;
#pragma unroll
            for (int j = 0; j < 4; ++j) {
                pf_d[j] = *(const float4*)(dp2 + n0 + 4 * j);
                pf_a[j] = *(const int4*)(cp2 + n0 + 4 * j);
                pf_b[j] = *(const int4*)(cp2 + NNZ + n0 + 4 * j);
            }
        }

        // ---- collect candidates >= tau via ballot compaction (packed u64) ----
#pragma unroll 1
        for (int j = 0; j < EPT; ++j) {
            bool q = (p[j] >= tau);
            uint64_t mask = __ballot(q);
            if (mask) {
                int base;
                if (lane == 0) base = atomicAdd(&scnt, __builtin_popcountll(mask));
                base = __shfl(base, 0);
                if (q) {
                    uint32_t idx16 = (uint32_t)((b << 12) | (n0 + j));
                    cand_pk[base + lane_offset(mask)] =
                        ((uint64_t)ord_enc(p[j]) << 32) | (uint64_t)((idx16 ^ 0xFFFFu) & 0xFFFFu);
                }
            }
        }
        __syncthreads();                                     // S2

        // local exact sorted top-16 -> publish data slots, then commit word
        if (wv == 0) {
            uint64_t q = wave_sel16_u64(scnt, cand_pk, lane);
            if (lane < BEAMS) {
                __hip_atomic_store(&slots[b * BEAMS + lane],
                                   q | ((uint64_t)tag << 16),
                                   __ATOMIC_RELAXED, __HIP_MEMORY_SCOPE_AGENT);
            }
            if (lane == 0) {
                __hip_atomic_store(&commit[b * 8], (uint64_t)tag,
                                   __ATOMIC_RELAXED, __HIP_MEMORY_SCOPE_AGENT);
            }
        }

        // ---- detection: 16 threads poll 16 commit lines (low contention) ----
        if (tid < NWG) {
            while (__hip_atomic_load(&commit[tid * 8], __ATOMIC_RELAXED,
                                     __HIP_MEMORY_SCOPE_AGENT) != (uint64_t)tag) {
                __builtin_amdgcn_s_sleep(8);
            }
        }
        __syncthreads();                                     // S3 (all slots committed)

        // one-shot slot read; per-entry tag guards rare store reordering
        uint64_t pk;
        do {
            pk = __hip_atomic_load(&slots[tid], __ATOMIC_RELAXED,
                                   __HIP_MEMORY_SCOPE_AGENT);
            if (((uint32_t)(pk >> 16) & 0xFFFFu) == tag) break;
            __builtin_amdgcn_s_sleep(1);
        } while (true);

        if ((tid & 15) == 0) headq[tid >> 4] = pk;   // list heads (rank 0)
        if (tid == 0) scnt = 0;
        __syncthreads();                                     // S4

        // tau_g = min of the 16 list heads (valid lower bound). One ballot round.
        uint64_t tq = headq[0];
#pragma unroll
        for (int k = 1; k < NWG; ++k) tq = (headq[k] < tq) ? headq[k] : tq;
        {
            bool qq = (pk >= tq);
            uint64_t mask = __ballot(qq);
            int base;
            if (lane == 0) base = atomicAdd(&scnt, __builtin_popcountll(mask));
            base = __shfl(base, 0);
            if (qq) cand_pk[base + lane_offset(mask)] = pk;
        }
        __syncthreads();                                     // S5

        if (wv == 0) {
            uint64_t q = wave_sel16_u64(scnt, cand_pk, lane);
            if (lane < BEAMS) respk[lane] = q;
        }
        __syncthreads();                                     // S6

        // state update from registers; WG0 writes outputs
        {
            uint64_t qb = respk[b];
            int idx = (int)((qb & 0xFFFFu) ^ 0xFFFFu);
            int n = idx & (NNZ - 1);
            r0i = cp[n];
            r1i = cp[NNZ + n];
            lpsb = ord_dec((uint32_t)(qb >> 32));
        }
        if (b == 0 && tid < BEAMS) {
            uint64_t q = respk[tid];
            int idx = (int)((q & 0xFFFFu) ^ 0xFFFFu);
            int n = idx & (NNZ - 1);
            out[BEAMS + (size_t)t * BEAMS + tid] = (float)cp[n];
            out[BEAMS + (size_t)TSTEPS * BEAMS + (size_t)t * BEAMS + tid] = (float)cp[NNZ + n];
            if (t == TSTEPS - 1) out[tid] = ord_dec((uint32_t)(q >> 32));
        }
        __syncthreads();                                     // protects respk/cand reuse
    }
}

extern "C" void kernel_launch(void* const* d_in, const int* in_sizes, int n_in,
                              void* d_out, int out_size, void* d_ws, size_t ws_size,
                              hipStream_t stream) {
    const float* p0        = (const float*)d_in[0];
    const float* p1        = (const float*)d_in[1];
    const float* ll_data   = (const float*)d_in[2];
    const int*   ll_coords = (const int*)d_in[3];
    const int*   x0i       = (const int*)d_in[4];
    const int*   x1i       = (const int*)d_in[5];
    float* outp = (float*)d_out;

    float* sc   = (float*)d_ws;                       // 32 MB scaled tables
    float* mArr = sc + (size_t)2 * KDIM * KDIM;       // 4096
    float* lArr = mArr + 2 * KDIM;                    // 4096
    uint64_t* gslot   = (uint64_t*)(lArr + 2 * KDIM); // [2][256] packed slots
    uint64_t* gcommit = gslot + 2 * NWG * BEAMS;      // [2][16] 64B-strided commits
    // No init needed: 0xAA poison -> tag 0xAAAA... never matches real tags.

    scale_kernel<<<(2 * KDIM * KDIM / 4) / 256, 256, 0, stream>>>(p0, p1, sc);
    rowstat_kernel<<<2 * KDIM, 256, 0, stream>>>(sc, mArr, lArr);
    beam_kernel<<<NWG, 256, 0, stream>>>(sc, mArr, lArr, ll_data, ll_coords,
                                         x0i, x1i, outp, gslot, gcommit);
}

// Round 8
// 17515.691 us; speedup vs baseline: 1.0612x; 1.0612x over previous
//
#include <hip/hip_runtime.h>
#include <hip/hip_bf16.h>
#include <math.h>
#include <stdint.h>

#define KDIM   2048
#define TSTEPS 1024
#define NNZ    4096
#define BEAMS  16
#define NWG    16               // one workgroup per beam
#define EPT    16               // evals per thread (NNZ / 256)
#define LCAP   4096             // LDS candidate capacity == max possible

// posterior in the reference's exact association order:
// ((lps + d) + ((v0 - m0) - L0)) + ((v1 - m1) - L1)
__device__ __forceinline__ float post_val(float lpsb, float d,
                                          float v0, float mm0, float ll0,
                                          float v1, float mm1, float ll1) {
    return ((lpsb + d) + ((v0 - mm0) - ll0)) + ((v1 - mm1) - ll1);
}

// order-preserving float<->uint32 map
__device__ __forceinline__ uint32_t ord_enc(float f) {
    uint32_t u = __float_as_uint(f);
    return (u & 0x80000000u) ? ~u : (u | 0x80000000u);
}
__device__ __forceinline__ float ord_dec(uint32_t u) {
    return __uint_as_float((u & 0x80000000u) ? (u & 0x7FFFFFFFu) : ~u);
}

__device__ __forceinline__ int lane_offset(uint64_t mask) {
    return __builtin_amdgcn_mbcnt_hi((uint32_t)(mask >> 32),
           __builtin_amdgcn_mbcnt_lo((uint32_t)mask, 0u));
}

// ---------- kernel 1: scaled tables = prior / 0.7 (true IEEE divide) ----------
__global__ void scale_kernel(const float* __restrict__ p0,
                             const float* __restrict__ p1,
                             float* __restrict__ sc) {
    const int NF4 = (KDIM * KDIM) / 4;
    int i = blockIdx.x * blockDim.x + threadIdx.x;
    float4 v;
    if (i < NF4) v = ((const float4*)p0)[i];
    else         v = ((const float4*)p1)[i - NF4];
    v.x = v.x / 0.7f; v.y = v.y / 0.7f; v.z = v.z / 0.7f; v.w = v.w / 0.7f;
    ((float4*)sc)[i] = v;
}

// ---------- kernel 2: per-row max + log-sum-exp of the scaled rows ----------
__global__ void rowstat_kernel(const float* __restrict__ sc,
                               float* __restrict__ mArr,
                               float* __restrict__ lArr) {
    __shared__ float red[4];
    __shared__ float bm;
    const int r = blockIdx.x;
    const float* row = sc + (size_t)r * KDIM;
    const int tid = threadIdx.x;
    const int lane = tid & 63, wv = tid >> 6;

    float4 a = ((const float4*)row)[tid];
    float4 b = ((const float4*)row)[tid + 256];
    float m = fmaxf(fmaxf(fmaxf(a.x, a.y), fmaxf(a.z, a.w)),
                    fmaxf(fmaxf(b.x, b.y), fmaxf(b.z, b.w)));
    for (int s = 32; s; s >>= 1) m = fmaxf(m, __shfl_xor(m, s));
    if (lane == 0) red[wv] = m;
    __syncthreads();
    if (tid == 0) bm = fmaxf(fmaxf(red[0], red[1]), fmaxf(red[2], red[3]));
    __syncthreads();
    const float mm = bm;

    float s = expf(a.x - mm);
    s += expf(a.y - mm); s += expf(a.z - mm); s += expf(a.w - mm);
    s += expf(b.x - mm); s += expf(b.y - mm); s += expf(b.z - mm); s += expf(b.w - mm);
    for (int sh = 32; sh; sh >>= 1) s += __shfl_xor(s, sh);
    __syncthreads();
    if (lane == 0) red[wv] = s;
    __syncthreads();
    if (tid == 0) {
        float S = ((red[0] + red[1]) + red[2]) + red[3];
        mArr[r] = mm;
        lArr[r] = logf(S);
    }
}

// float-only 64-lane bitonic (descending): returns 16th-largest, broadcast
__device__ __forceinline__ float wave16th_f(float v, int lane) {
    for (int k = 2; k <= 64; k <<= 1) {
        for (int j = k >> 1; j > 0; j >>= 1) {
            float ov = __shfl_xor(v, j);
            bool lower = (lane & j) == 0;
            bool up    = (lane & k) == 0;
            bool iwin  = v > ov;
            bool take  = (lower == up) ? !iwin : iwin;
            if (take) v = ov;
        }
    }
    return __shfl(v, 15);
}

// u64 64-lane bitonic sort (descending): rank r lands in lane r
__device__ __forceinline__ uint64_t bsort64(uint64_t v, int lane) {
    for (int k = 2; k <= 64; k <<= 1) {
        for (int j = k >> 1; j > 0; j >>= 1) {
            uint64_t ov = __shfl_xor((unsigned long long)v, j);
            bool lower = (lane & j) == 0;
            bool up    = (lane & k) == 0;
            bool iwin  = v > ov;
            bool take  = (lower == up) ? !iwin : iwin;
            if (take) v = ov;
        }
    }
    return v;
}

// wave0: exact sorted top-16 of lds[0..C) (u64 desc). Lane r<16 returns rank r.
// Values are unique and nonzero by construction; 0 is the -inf sentinel.
__device__ __forceinline__ uint64_t wave_sel16_u64(int C, uint64_t* lds, int lane) {
    if (C <= 64) {
        uint64_t v = (lane < C) ? lds[lane] : 0;
        return bsort64(v, lane);
    }
    uint64_t res = 0;
    for (int rk = 0; rk < BEAMS; ++rk) {
        uint64_t bv = 0; int bj = -1;
        for (int j = lane; j < C; j += 64) {
            uint64_t v = lds[j];
            if (v > bv) { bv = v; bj = j; }
        }
        for (int s = 32; s; s >>= 1) {
            uint64_t ov = __shfl_xor((unsigned long long)bv, s);
            int      oj = __shfl_xor(bj, s);
            if (ov > bv) { bv = ov; bj = oj; }
        }
        if (lane == 0 && bj >= 0) lds[bj] = 0;
        if (lane == rk) res = bv;
    }
    return res;
}

// ---------- kernel 3: 16 WGs, LDS row staging, commit-word sync ----------
__global__ __launch_bounds__(256, 1) void beam_kernel(
    const float* __restrict__ sc,        // [2*2048][2048] scaled tables
    const float* __restrict__ mArr,      // [4096]
    const float* __restrict__ lArr,      // [4096]
    const float* __restrict__ ll_data,   // [1024][4096]
    const int*   __restrict__ ll_coords, // [1024][2][4096]
    const int*   __restrict__ x0i,
    const int*   __restrict__ x1i,
    float* __restrict__ out,
    uint64_t* __restrict__ gslot,        // [2][NWG*16] packed candidates
    uint64_t* __restrict__ gcommit)      // [2][NWG] commit words, 64B stride
{
    __shared__ float    wred[4];
    __shared__ int      scnt;
    __shared__ uint64_t cand_pk[LCAP];   // 32 KB
    __shared__ float    smArr[2 * KDIM]; // 16 KB — row stats cached in LDS
    __shared__ float    slArr[2 * KDIM]; // 16 KB
    __shared__ float    srow0[KDIM];     // 8 KB — this beam's prior0 row
    __shared__ float    srow1[KDIM];     // 8 KB — this beam's prior1 row
    __shared__ uint64_t headq[NWG];
    __shared__ uint64_t respk[BEAMS];

    const int tid  = threadIdx.x;
    const int lane = tid & 63;
    const int wv   = tid >> 6;
    const int b    = blockIdx.x;              // this WG's beam
    const float* sc1 = sc + (size_t)KDIM * KDIM;
    const int n0 = tid * EPT;

    // cache per-row normalizer stats in LDS (one-time, 32 KB)
    for (int i = tid; i < 2 * KDIM; i += 256) {
        smArr[i] = mArr[i];
        slArr[i] = lArr[i];
    }

    // beam state in registers (uniform across the WG)
    int   r0i  = x0i[b];
    int   r1i  = x1i[b];
    float lpsb = 0.0f;

    // prefetch step 0 stream data into registers
    float4 pf_d[4]; int4 pf_a[4], pf_b[4];
#pragma unroll
    for (int j = 0; j < 4; ++j) {
        pf_d[j] = *(const float4*)(ll_data + n0 + 4 * j);
        pf_a[j] = *(const int4*)(ll_coords + n0 + 4 * j);
        pf_b[j] = *(const int4*)(ll_coords + NNZ + n0 + 4 * j);
    }
    __syncthreads();

#pragma unroll 1
    for (int t = 0; t < TSTEPS; ++t) {
        const int* cp = ll_coords + (size_t)t * 2 * NNZ;
        uint64_t* slots  = gslot + (size_t)(t & 1) * (NWG * BEAMS);
        uint64_t* commit = gcommit + (size_t)(t & 1) * (NWG * 8);
        const uint32_t tag = (uint32_t)(t + 1);   // never matches 0xAAAA poison

        // ---- stage this beam's two rows into LDS (coalesced, 16 KB) ----
        {
            const float* r0g = sc  + (size_t)r0i * KDIM;
            const float* r1g = sc1 + (size_t)r1i * KDIM;
            float4 t0 = ((const float4*)r0g)[tid];
            float4 t1 = ((const float4*)r0g)[tid + 256];
            float4 t2 = ((const float4*)r1g)[tid];
            float4 t3 = ((const float4*)r1g)[tid + 256];
            ((float4*)srow0)[tid]       = t0;
            ((float4*)srow0)[tid + 256] = t1;
            ((float4*)srow1)[tid]       = t2;
            ((float4*)srow1)[tid + 256] = t3;
        }
        if (tid == 0) scnt = 0;
        const float mm0 = smArr[r0i],        ll0 = slArr[r0i];
        const float mm1 = smArr[KDIM + r1i], ll1 = slArr[KDIM + r1i];
        __syncthreads();                                     // S0 (rows staged)

        // ---- eval: 16 posteriors/thread, gathers from LDS ----
        float p[EPT];
        float best = -INFINITY;
#pragma unroll
        for (int j = 0; j < 4; ++j) {
            float4 d4 = pf_d[j]; int4 a4 = pf_a[j]; int4 b4 = pf_b[j];
            float va0 = srow0[a4.x], va1 = srow0[a4.y], va2 = srow0[a4.z], va3 = srow0[a4.w];
            float vb0 = srow1[b4.x], vb1 = srow1[b4.y], vb2 = srow1[b4.z], vb3 = srow1[b4.w];
            p[4*j+0] = post_val(lpsb, d4.x, va0, mm0, ll0, vb0, mm1, ll1);
            p[4*j+1] = post_val(lpsb, d4.y, va1, mm0, ll0, vb1, mm1, ll1);
            p[4*j+2] = post_val(lpsb, d4.z, va2, mm0, ll0, vb2, mm1, ll1);
            p[4*j+3] = post_val(lpsb, d4.w, va3, mm0, ll0, vb3, mm1, ll1);
            best = fmaxf(best, fmaxf(fmaxf(p[4*j+0], p[4*j+1]), fmaxf(p[4*j+2], p[4*j+3])));
        }

        // tau = max over waves of (16th-largest lane-best): valid lower bound
        float w16 = wave16th_f(best, lane);
        if (lane == 0) wred[wv] = w16;
        __syncthreads();                                     // S1
        const float tau = fmaxf(fmaxf(wred[0], wred[1]), fmaxf(wred[2], wred[3]));

        // prefetch next step's stream; loads fly under select/publish/poll
        {
            const int tp = (t + 1 < TSTEPS) ? t + 1 : t;
            const float* dp2 = ll_data + (size_t)tp * NNZ;
            const int*   cp2 = ll_coords + (size_t)tp * 2 * NNZ;
#pragma unroll
            for (int j = 0; j < 4; ++j) {
                pf_d[j] = *(const float4*)(dp2 + n0 + 4 * j);
                pf_a[j] = *(const int4*)(cp2 + n0 + 4 * j);
                pf_b[j] = *(const int4*)(cp2 + NNZ + n0 + 4 * j);
            }
        }

        // ---- collect candidates >= tau via ballot compaction (packed u64) ----
#pragma unroll 1
        for (int j = 0; j < EPT; ++j) {
            bool q = (p[j] >= tau);
            uint64_t mask = __ballot(q);
            if (mask) {
                int base;
                if (lane == 0) base = atomicAdd(&scnt, __builtin_popcountll(mask));
                base = __shfl(base, 0);
                if (q) {
                    uint32_t idx16 = (uint32_t)((b << 12) | (n0 + j));
                    cand_pk[base + lane_offset(mask)] =
                        ((uint64_t)ord_enc(p[j]) << 32) | (uint64_t)((idx16 ^ 0xFFFFu) & 0xFFFFu);
                }
            }
        }
        __syncthreads();                                     // S2

        // local exact sorted top-16 -> publish data slots, then commit word
        if (wv == 0) {
            uint64_t q = wave_sel16_u64(scnt, cand_pk, lane);
            if (lane < BEAMS) {
                __hip_atomic_store(&slots[b * BEAMS + lane],
                                   q | ((uint64_t)tag << 16),
                                   __ATOMIC_RELAXED, __HIP_MEMORY_SCOPE_AGENT);
            }
            if (lane == 0) {
                __hip_atomic_store(&commit[b * 8], (uint64_t)tag,
                                   __ATOMIC_RELAXED, __HIP_MEMORY_SCOPE_AGENT);
            }
        }

        // ---- detection: 16 threads poll 16 commit lines (low contention) ----
        if (tid < NWG) {
            while (__hip_atomic_load(&commit[tid * 8], __ATOMIC_RELAXED,
                                     __HIP_MEMORY_SCOPE_AGENT) != (uint64_t)tag) {
                __builtin_amdgcn_s_sleep(8);
            }
        }
        __syncthreads();                                     // S3 (all slots committed)

        // one-shot slot read; per-entry tag guards rare store reordering
        uint64_t pk;
        do {
            pk = __hip_atomic_load(&slots[tid], __ATOMIC_RELAXED,
                                   __HIP_MEMORY_SCOPE_AGENT);
            if (((uint32_t)(pk >> 16) & 0xFFFFu) == tag) break;
            __builtin_amdgcn_s_sleep(1);
        } while (true);

        if ((tid & 15) == 0) headq[tid >> 4] = pk;   // list heads (rank 0)
        if (tid == 0) scnt = 0;
        __syncthreads();                                     // S4

        // tau_g = min of the 16 list heads (valid lower bound). One ballot round.
        uint64_t tq = headq[0];
#pragma unroll
        for (int k = 1; k < NWG; ++k) tq = (headq[k] < tq) ? headq[k] : tq;
        {
            bool qq = (pk >= tq);
            uint64_t mask = __ballot(qq);
            int base;
            if (lane == 0) base = atomicAdd(&scnt, __builtin_popcountll(mask));
            base = __shfl(base, 0);
            if (qq) cand_pk[base + lane_offset(mask)] = pk;
        }
        __syncthreads();                                     // S5

        if (wv == 0) {
            uint64_t q = wave_sel16_u64(scnt, cand_pk, lane);
            if (lane < BEAMS) respk[lane] = q;
        }
        __syncthreads();                                     // S6

        // state update from registers; WG0 writes outputs
        {
            uint64_t qb = respk[b];
            int idx = (int)((qb & 0xFFFFu) ^ 0xFFFFu);
            int n = idx & (NNZ - 1);
            r0i = cp[n];
            r1i = cp[NNZ + n];
            lpsb = ord_dec((uint32_t)(qb >> 32));
        }
        if (b == 0 && tid < BEAMS) {
            uint64_t q = respk[tid];
            int idx = (int)((q & 0xFFFFu) ^ 0xFFFFu);
            int n = idx & (NNZ - 1);
            out[BEAMS + (size_t)t * BEAMS + tid] = (float)cp[n];
            out[BEAMS + (size_t)TSTEPS * BEAMS + (size_t)t * BEAMS + tid] = (float)cp[NNZ + n];
            if (t == TSTEPS - 1) out[tid] = ord_dec((uint32_t)(q >> 32));
        }
        __syncthreads();                                     // protects respk/cand reuse
    }
}

extern "C" void kernel_launch(void* const* d_in, const int* in_sizes, int n_in,
                              void* d_out, int out_size, void* d_ws, size_t ws_size,
                              hipStream_t stream) {
    const float* p0        = (const float*)d_in[0];
    const float* p1        = (const float*)d_in[1];
    const float* ll_data   = (const float*)d_in[2];
    const int*   ll_coords = (const int*)d_in[3];
    const int*   x0i       = (const int*)d_in[4];
    const int*   x1i       = (const int*)d_in[5];
    float* outp = (float*)d_out;

    float* sc   = (float*)d_ws;                       // 32 MB scaled tables
    float* mArr = sc + (size_t)2 * KDIM * KDIM;       // 4096
    float* lArr = mArr + 2 * KDIM;                    // 4096
    uint64_t* gslot   = (uint64_t*)(lArr + 2 * KDIM); // [2][256] packed slots
    uint64_t* gcommit = gslot + 2 * NWG * BEAMS;      // [2][16] 64B-strided commits
    // No init needed: 0xAA poison -> tag 0xAAAA... never matches real tags.

    scale_kernel<<<(2 * KDIM * KDIM / 4) / 256, 256, 0, stream>>>(p0, p1, sc);
    rowstat_kernel<<<2 * KDIM, 256, 0, stream>>>(sc, mArr, lArr);
    beam_kernel<<<NWG, 256, 0, stream>>>(sc, mArr, lArr, ll_data, ll_coords,
                                         x0i, x1i, outp, gslot, gcommit);
}